// Round 12
// baseline (111.264 us; speedup 1.0000x reference)
//
#include <hip/hip_runtime.h>
#include <math.h>

#define HDIM 256
#define H4   64          // HDIM / 4
#define EPSN 1e-8f       // torch F.cosine_similarity norm clamp
#define CT   80          // c-tile per block -> grid = 250 blocks (no CU tail)
#define KC   8           // f4 k-steps per chunk (32 floats)
#define NCH  8           // chunks: KC*NCH = H4

typedef unsigned long long u64;
typedef unsigned int       u32;

// Monotonic (value, index) packing: larger key == better candidate under
// lax.top_k semantics (descending value, lower index wins ties).
__device__ __forceinline__ u64 make_key(float v, int idx) {
    u32 u = __float_as_uint(v);
    u ^= (u & 0x80000000u) ? 0xFFFFFFFFu : 0x80000000u;
    return ((u64)u << 32) | (u32)(~idx);
}
__device__ __forceinline__ float key_val(u64 k) {
    u32 u = (u32)(k >> 32);
    u ^= (u & 0x80000000u) ? 0x80000000u : 0xFFFFFFFFu;
    return __uint_as_float(u);
}
__device__ __forceinline__ int key_idx(u64 k) { return (int)(~(u32)k); }

__device__ __forceinline__ void insert8(u64* ls, u64 k) {
    if (k > ls[7]) {
        ls[7] = k;
        #pragma unroll
        for (int j = 7; j > 0; --j)
            if (ls[j] > ls[j-1]) { u64 tmp = ls[j]; ls[j] = ls[j-1]; ls[j-1] = tmp; }
    }
}

// ---------------------------------------------------------------------------
// Kernel 1 (sims): K-SPLIT 8-wave variant of the round-8 kernel.
// 512 threads: waves 0-3 ("even half") compute K-chunks 0,2,4,6; waves 4-7
// chunks 1,3,5,7. Each half runs the EXACT round-8 inner loop on the full
// 80c x 64b tile (same 9 ds_read_b128 + 116 fmaf per lane-step). 4 LDS chunk
// buffers (2 pairs, double-buffered by pair). Occupancy 1 -> 2 waves/SIMD:
// every latency stall now has a partner wave. Partial acc/ee/qq summed via
// LDS at the end (one fp32 add reorder, ~1e-7 on scores; selection safe).
// ---------------------------------------------------------------------------
__global__ __launch_bounds__(512)
void sims_kernel(const float4* __restrict__ q4, const float4* __restrict__ emb4,
                 float* __restrict__ sims, int C, int B) {
    __shared__ float4 e_lds[4][CT][KC + 1];   // 46.1 KB: [pair*2+sub][row][col]
    __shared__ float4 q_lds[4][64][KC + 1];   // 36.9 KB
    __shared__ float  part[256][33];          // 33.8 KB reduce scratch (padded)

    const int t    = threadIdx.x;
    const int half = t >> 8;          // 0: even chunks, 1: odd chunks
    const int tl   = t & 255;         // role within half (== round-8 t)
    const int tc   = tl & 15;         // c-rows: tc + 16i, i < 5
    const int tb   = tl >> 4;         // b-rows: tb + 16j, j < 4
    const int c0   = blockIdx.x * CT;
    const float4 z = make_float4(0.f, 0.f, 0.f, 0.f);

    // staging regs for one pair (2 chunks): e = 1280 f4, q = 1024 f4
    float4 pe0, pe1, pe2, pq0, pq1;

    #define DECODE_E(idx, cb, dst) do {                                       \
        int _sub = (idx) >= 640, _loc = (idx) - _sub * 640;                   \
        int _r = _loc >> 3, _col = _loc & 7; int _gc = c0 + _r;               \
        dst = (_gc < C) ? emb4[(size_t)_gc * H4 + ((cb) + _sub) * KC + _col] : z; \
    } while (0)
    #define DECODE_Q(idx, cb, dst) do {                                       \
        int _sub = (idx) >= 512, _loc = (idx) - _sub * 512;                   \
        int _rr = _loc >> 3, _col = _loc & 7;                                 \
        dst = (_rr < B) ? q4[(size_t)_rr * H4 + ((cb) + _sub) * KC + _col] : z; \
    } while (0)
    #define LOAD_PAIR(cb) do {                                                \
        DECODE_E(t, cb, pe0); DECODE_E(t + 512, cb, pe1);                     \
        if (t < 256) DECODE_E(t + 1024, cb, pe2);                             \
        DECODE_Q(t, cb, pq0); DECODE_Q(t + 512, cb, pq1);                     \
    } while (0)
    #define WRITE_E(idx, slot, src) do {                                      \
        int _sub = (idx) >= 640, _loc = (idx) - _sub * 640;                   \
        e_lds[(slot) * 2 + _sub][_loc >> 3][_loc & 7] = src;                  \
    } while (0)
    #define WRITE_Q(idx, slot, src) do {                                      \
        int _sub = (idx) >= 512, _loc = (idx) - _sub * 512;                   \
        q_lds[(slot) * 2 + _sub][_loc >> 3][_loc & 7] = src;                  \
    } while (0)
    #define WRITE_PAIR(slot) do {                                             \
        WRITE_E(t, slot, pe0); WRITE_E(t + 512, slot, pe1);                   \
        if (t < 256) WRITE_E(t + 1024, slot, pe2);                            \
        WRITE_Q(t, slot, pq0); WRITE_Q(t + 512, slot, pq1);                   \
    } while (0)

    float acc[5][4], ee[5], qq[4];
    #pragma unroll
    for (int i = 0; i < 5; ++i) {
        ee[i] = 0.f;
        #pragma unroll
        for (int j = 0; j < 4; ++j) acc[i][j] = 0.f;
    }
    #pragma unroll
    for (int j = 0; j < 4; ++j) qq[j] = 0.f;

    LOAD_PAIR(0);         // chunks 0,1 -> pair slot 0
    WRITE_PAIR(0);
    __syncthreads();

    for (int g = 0; g < 4; ++g) {                // supersteps of 2 chunks
        if (g < 3) LOAD_PAIR(2 * (g + 1));       // prefetch next pair (async)

        const int bi = ((g & 1) << 1) + half;    // my buffer this superstep
        #pragma unroll
        for (int s = 0; s < KC; ++s) {
            float4 a[5], b[4];
            #pragma unroll
            for (int i = 0; i < 5; ++i) a[i] = e_lds[bi][tc + 16 * i][s];
            #pragma unroll
            for (int j = 0; j < 4; ++j) b[j] = q_lds[bi][tb + 16 * j][s];

            #pragma unroll
            for (int i = 0; i < 5; ++i)
                ee[i] = fmaf(a[i].x,a[i].x, fmaf(a[i].y,a[i].y,
                        fmaf(a[i].z,a[i].z, fmaf(a[i].w,a[i].w, ee[i]))));
            #pragma unroll
            for (int j = 0; j < 4; ++j)
                qq[j] = fmaf(b[j].x,b[j].x, fmaf(b[j].y,b[j].y,
                        fmaf(b[j].z,b[j].z, fmaf(b[j].w,b[j].w, qq[j]))));
            #pragma unroll
            for (int i = 0; i < 5; ++i)
                #pragma unroll
                for (int j = 0; j < 4; ++j)
                    acc[i][j] = fmaf(a[i].x,b[j].x, fmaf(a[i].y,b[j].y,
                                fmaf(a[i].z,b[j].z, fmaf(a[i].w,b[j].w, acc[i][j]))));
        }

        if (g < 3) {
            WRITE_PAIR((g + 1) & 1);   // other slot: not read this superstep
            __syncthreads();
        }
    }

    // ---- combine halves: even half spills partials, odd half finishes ----
    __syncthreads();
    if (half == 0) {
        float* dst = &part[tl][0];
        #pragma unroll
        for (int i = 0; i < 5; ++i)
            #pragma unroll
            for (int j = 0; j < 4; ++j) dst[i * 4 + j] = acc[i][j];
        #pragma unroll
        for (int i = 0; i < 5; ++i) dst[20 + i] = ee[i];
        #pragma unroll
        for (int j = 0; j < 4; ++j) dst[25 + j] = qq[j];
    }
    __syncthreads();
    if (half == 1) {
        const float* src = &part[tl][0];
        #pragma unroll
        for (int i = 0; i < 5; ++i)
            #pragma unroll
            for (int j = 0; j < 4; ++j) acc[i][j] += src[i * 4 + j];
        #pragma unroll
        for (int i = 0; i < 5; ++i) ee[i] += src[20 + i];
        #pragma unroll
        for (int j = 0; j < 4; ++j) qq[j] += src[25 + j];

        float einv[5], qinv[4];
        #pragma unroll
        for (int i = 0; i < 5; ++i) einv[i] = 1.f / fmaxf(sqrtf(ee[i]), EPSN);
        #pragma unroll
        for (int j = 0; j < 4; ++j) qinv[j] = 1.f / fmaxf(sqrtf(qq[j]), EPSN);

        #pragma unroll
        for (int j = 0; j < 4; ++j) {
            int b = tb + 16 * j;
            if (b < B) {
                #pragma unroll
                for (int i = 0; i < 5; ++i) {
                    int c = c0 + tc + 16 * i;
                    if (c < C) sims[(size_t)b * C + c] = acc[i][j] * qinv[j] * einv[i];
                }
            }
        }
    }
    #undef WRITE_PAIR
    #undef WRITE_Q
    #undef WRITE_E
    #undef LOAD_PAIR
    #undef DECODE_Q
    #undef DECODE_E
}

// ---------------------------------------------------------------------------
// Kernel 2 (topk_scan): identical to round 8. grid = B*4 + 1. Blocks (b,seg):
// scan C/4 of row b (8-deep batched loads) -> per-block top-8 -> cand.
// Last block: is_compressed storage-layout detection (validated rounds 1-11).
// ---------------------------------------------------------------------------
__global__ __launch_bounds__(256)
void topk_scan(const float* __restrict__ sims, const u32* __restrict__ mask4,
               u64* __restrict__ cand, int* __restrict__ flags, int C, int B) {
    const int t = threadIdx.x;

    if (blockIdx.x == (unsigned)(B * 4)) {   // ---- mask layout detection ----
        __shared__ int red0[4], red1[4];
        int lo = 0, lg = 0;
        const int n4 = C >> 2;
        int i = t;
        for (; i + 768 < n4; i += 1024) {
            u32 v0 = mask4[i], v1 = mask4[i + 256], v2 = mask4[i + 512], v3 = mask4[i + 768];
            u32 o = v0 | v1 | v2 | v3;
            if (o & 0xFFFFFF00u) lo = 1;   // nonzero byte at offset 1..3
            if (o & 0xFEFEFEFEu) lg = 1;   // any byte value > 1
        }
        for (; i < n4; i += 256) {
            u32 v = mask4[i];
            if (v & 0xFFFFFF00u) lo = 1;
            if (v & 0xFEFEFEFEu) lg = 1;
        }
        const unsigned char* mb = (const unsigned char*)mask4;
        for (int j = (n4 << 2) + t; j < C; j += 256) {
            unsigned char v = mb[j];
            if (v > 1) lg = 1;
            if ((j & 3) != 0 && v != 0) lo = 1;
        }
        lo = __any(lo); lg = __any(lg);
        if ((t & 63) == 0) { red0[t >> 6] = lo; red1[t >> 6] = lg; }
        __syncthreads();
        if (t == 0) {
            flags[0] = red0[0] | red0[1] | red0[2] | red0[3];
            flags[1] = red1[0] | red1[1] | red1[2] | red1[3];
        }
        return;
    }

    __shared__ u64 sh[256 * 8];   // 16 KB
    const int b    = blockIdx.x >> 2;
    const int seg  = blockIdx.x & 3;
    const int slen = (C + 3) >> 2;
    const int cbeg = seg * slen;
    const int cend = min(cbeg + slen, C);
    const float* row = sims + (size_t)b * C;

    u64 ls[8];
    #pragma unroll
    for (int j = 0; j < 8; ++j) ls[j] = 0ull;

    int c = cbeg + t;
    for (; c + 7 * 256 < cend; c += 8 * 256) {     // 8 independent loads first
        float v[8];
        #pragma unroll
        for (int u = 0; u < 8; ++u) v[u] = row[c + u * 256];
        #pragma unroll
        for (int u = 0; u < 8; ++u) insert8(ls, make_key(v[u], c + u * 256));
    }
    for (; c < cend; c += 256) insert8(ls, make_key(row[c], c));

    #pragma unroll
    for (int j = 0; j < 8; ++j) sh[t * 8 + j] = ls[j];
    __syncthreads();

    if (t < 64) {
        u64 m[8];
        #pragma unroll
        for (int j = 0; j < 8; ++j) m[j] = 0ull;
        for (int tt = 0; tt < 4; ++tt) {
            const u64* pp = &sh[(t * 4 + tt) * 8];
            #pragma unroll
            for (int j = 0; j < 8; ++j) {
                u64 k = pp[j];
                if (k <= m[7]) break;           // pp[] sorted descending
                m[7] = k;
                #pragma unroll
                for (int q = 7; q > 0; --q)
                    if (m[q] > m[q-1]) { u64 tmp = m[q]; m[q] = m[q-1]; m[q-1] = tmp; }
            }
        }
        for (int r = 0; r < 8; ++r) {
            u64 best = m[0];
            #pragma unroll
            for (int off = 32; off; off >>= 1) {
                u64 o = __shfl_xor(best, off, 64);
                if (o > best) best = o;
            }
            if (m[0] == best) {                 // unique owner pops
                #pragma unroll
                for (int q = 0; q < 7; ++q) m[q] = m[q+1];
                m[7] = 0ull;
            }
            if (t == 0) cand[((size_t)b * 4 + seg) * 8 + r] = best;
        }
    }
}

// ---------------------------------------------------------------------------
// Kernel 3 (gather): identical to round 8. TWO blocks per (b, j); each merges
// b's 32 segment candidates in-register -> rank-j key gives episode index AND
// score, then copies its half episode.
// ---------------------------------------------------------------------------
__global__ __launch_bounds__(256)
void gather_kernel(const float* __restrict__ episodes,    // [C][S][256]
                   const float* __restrict__ compressed,  // [C][Cs][256]
                   const void* __restrict__ is_comp,
                   const u64* __restrict__ cand,          // [B][4][8]
                   const int* __restrict__ flags,
                   float* __restrict__ out,               // [B*8][S*256]
                   float* __restrict__ scores_out,        // [B*8]
                   int S, int Cs) {
    const int bj = blockIdx.x >> 1;
    const int h  = blockIdx.x & 1;
    const int b  = bj >> 3;
    const int j  = bj & 7;

    // merge 32 candidate keys -> top-8 (sorted desc); rank j = ls[j]
    const u64* cb = cand + (size_t)b * 32;
    u64 ls[8];
    #pragma unroll
    for (int q = 0; q < 8; ++q) ls[q] = 0ull;
    #pragma unroll
    for (int i = 0; i < 32; ++i) insert8(ls, cb[i]);

    const u64 kj  = ls[j];
    const int idx = key_idx(kj);
    if (h == 0 && threadIdx.x == 0) scores_out[bj] = key_val(kj);

    const int f_off = flags[0], f_gt1 = flags[1];
    bool comp;
    if      (f_gt1) comp = ((const float*)is_comp)[idx] != 0.f;
    else if (f_off) comp = ((const unsigned char*)is_comp)[idx] != 0;
    else            comp = ((const int*)is_comp)[idx] != 0;

    const int n4   = S * H4;       // 2048
    const int c4   = Cs * H4;      // 1024
    const int half = n4 >> 1;      // 1024
    const int v0   = h * half;

    const float4* full4 = (const float4*)episodes   + (size_t)idx * n4;
    const float4* cmp4  = (const float4*)compressed + (size_t)idx * c4;
    float4* out4 = (float4*)out + (size_t)bj * n4;
    const float4 z = make_float4(0.f, 0.f, 0.f, 0.f);

    if (comp) {
        #pragma unroll 4
        for (int v = v0 + threadIdx.x; v < v0 + half; v += 256)
            out4[v] = (v < c4) ? cmp4[v] : z;
    } else {
        #pragma unroll 4
        for (int v = v0 + threadIdx.x; v < v0 + half; v += 256)
            out4[v] = full4[v];
    }
}

// ---------------------------------------------------------------------------
extern "C" void kernel_launch(void* const* d_in, const int* in_sizes, int n_in,
                              void* d_out, int out_size, void* d_ws, size_t ws_size,
                              hipStream_t stream) {
    const float* query      = (const float*)d_in[0];
    const float* episodes   = (const float*)d_in[1];
    const float* compressed = (const float*)d_in[2];
    const float* emb        = (const float*)d_in[3];
    const void*  is_comp    = d_in[4];
    // d_in[5] is k (device scalar); fixed at 8 by the problem setup.

    const int B  = in_sizes[0] / HDIM;        // 64
    const int C  = in_sizes[3] / HDIM;        // 20000
    const int S  = in_sizes[1] / (C * HDIM);  // 32
    const int Cs = in_sizes[2] / (C * HDIM);  // 16
    const int K  = 8;

    float* out        = (float*)d_out;
    float* scores_out = out + (size_t)B * K * S * HDIM;

    // scratch layout in d_ws (fully rewritten every call -> deterministic):
    float* sims    = (float*)d_ws;                             // B*C floats
    size_t simsOff = (((size_t)B * C * sizeof(float)) + 255) & ~(size_t)255;
    u64*   cand    = (u64*)((char*)d_ws + simsOff);            // B*4*8 u64
    int*   flags   = (int*)(cand + (size_t)B * 32);            // 2 ints

    sims_kernel<<<(C + CT - 1) / CT, 512, 0, stream>>>(
        (const float4*)query, (const float4*)emb, sims, C, B);
    topk_scan<<<B * 4 + 1, 256, 0, stream>>>(sims, (const u32*)is_comp,
                                             cand, flags, C, B);
    gather_kernel<<<B * K * 2, 256, 0, stream>>>(episodes, compressed, is_comp,
                                                 cand, flags, out, scores_out,
                                                 S, Cs);
}

// Round 13
// 55.335 us; speedup vs baseline: 2.0107x; 2.0107x over previous
//
#include <hip/hip_runtime.h>
#include <math.h>

#define HDIM 256
#define H4   64          // HDIM / 4
#define EPSN 1e-8f       // torch F.cosine_similarity norm clamp
#define CT   80          // c-tile per block -> grid = 250 blocks (no CU tail)
#define KC   8           // f4 k-steps per chunk (32 floats)
#define NCH  8           // chunks: KC*NCH = H4

typedef unsigned long long u64;
typedef unsigned int       u32;

// Monotonic (value, index) packing: larger key == better candidate under
// lax.top_k semantics (descending value, lower index wins ties).
__device__ __forceinline__ u64 make_key(float v, int idx) {
    u32 u = __float_as_uint(v);
    u ^= (u & 0x80000000u) ? 0xFFFFFFFFu : 0x80000000u;
    return ((u64)u << 32) | (u32)(~idx);
}
__device__ __forceinline__ float key_val(u64 k) {
    u32 u = (u32)(k >> 32);
    u ^= (u & 0x80000000u) ? 0x80000000u : 0xFFFFFFFFu;
    return __uint_as_float(u);
}
__device__ __forceinline__ int key_idx(u64 k) { return (int)(~(u32)k); }

__device__ __forceinline__ void insert8(u64* ls, u64 k) {
    if (k > ls[7]) {
        ls[7] = k;
        #pragma unroll
        for (int j = 7; j > 0; --j)
            if (ls[j] > ls[j-1]) { u64 tmp = ls[j]; ls[j] = ls[j-1]; ls[j-1] = tmp; }
    }
}

// ---------------------------------------------------------------------------
// Kernel 1 (sims): ROUND-8 KERNEL (measured best: dbuf LDS, 5x4 reg tile,
// fused norms, 1 barrier/chunk) + one addition: block NT (the 251st, running
// on an otherwise-idle CU) performs the is_compressed layout detection that
// previously serialized as topk_scan's 257th block.
// ---------------------------------------------------------------------------
__global__ __launch_bounds__(256)
void sims_kernel(const float4* __restrict__ q4, const float4* __restrict__ emb4,
                 const u32* __restrict__ mask4, float* __restrict__ sims,
                 int* __restrict__ flags, int C, int B, int NT) {
    const int t = threadIdx.x;

    if (blockIdx.x == (unsigned)NT) {        // ---- mask layout detection ----
        __shared__ int red0[4], red1[4];
        int lo = 0, lg = 0;
        const int n4 = C >> 2;
        int i = t;
        for (; i + 768 < n4; i += 1024) {
            u32 v0 = mask4[i], v1 = mask4[i + 256], v2 = mask4[i + 512], v3 = mask4[i + 768];
            u32 o = v0 | v1 | v2 | v3;
            if (o & 0xFFFFFF00u) lo = 1;   // nonzero byte at offset 1..3
            if (o & 0xFEFEFEFEu) lg = 1;   // any byte value > 1
        }
        for (; i < n4; i += 256) {
            u32 v = mask4[i];
            if (v & 0xFFFFFF00u) lo = 1;
            if (v & 0xFEFEFEFEu) lg = 1;
        }
        const unsigned char* mb = (const unsigned char*)mask4;
        for (int j = (n4 << 2) + t; j < C; j += 256) {
            unsigned char v = mb[j];
            if (v > 1) lg = 1;
            if ((j & 3) != 0 && v != 0) lo = 1;
        }
        lo = __any(lo); lg = __any(lg);
        if ((t & 63) == 0) { red0[t >> 6] = lo; red1[t >> 6] = lg; }
        __syncthreads();
        if (t == 0) {
            flags[0] = red0[0] | red0[1] | red0[2] | red0[3];
            flags[1] = red1[0] | red1[1] | red1[2] | red1[3];
        }
        return;
    }

    __shared__ float4 e_lds[2][CT][KC + 1];   // 2 x 11.25 KB
    __shared__ float4 q_lds[2][64][KC + 1];   // 2 x  9.0 KB   (total 41.5 KB)

    const int c0 = blockIdx.x * CT;
    const int tc = t & 15;       // c-rows: tc + 16i, i < 5
    const int tb = t >> 4;       // b-rows: tb + 16j, j < 4
    const float4 z = make_float4(0.f, 0.f, 0.f, 0.f);

    float4 pe0, pe1, pe2, pq0, pq1;

    #define LOAD_E(idx, ch, dst) do {                                        \
        int _r = (idx) >> 3, _cl = (idx) & 7; int _gc = c0 + _r;             \
        dst = (_gc < C) ? emb4[(size_t)_gc * H4 + (ch) * KC + _cl] : z;      \
    } while (0)
    #define LOAD_Q(idx, ch, dst) do {                                        \
        int _r = (idx) >> 3, _cl = (idx) & 7;                                \
        dst = (_r < B) ? q4[(size_t)_r * H4 + (ch) * KC + _cl] : z;          \
    } while (0)
    #define LOAD_CHUNK(ch) do {                                              \
        LOAD_E(t,       ch, pe0); LOAD_E(t + 256, ch, pe1);                  \
        if (t < 128) LOAD_E(t + 512, ch, pe2);                               \
        LOAD_Q(t,       ch, pq0); LOAD_Q(t + 256, ch, pq1);                  \
    } while (0)
    #define WRITE_CHUNK(pp) do {                                             \
        { int r = t >> 3,       cl = t & 7;       e_lds[pp][r][cl] = pe0; }  \
        { int r = (t+256) >> 3, cl = (t+256) & 7; e_lds[pp][r][cl] = pe1; }  \
        if (t < 128) { int r = (t+512) >> 3, cl = (t+512) & 7; e_lds[pp][r][cl] = pe2; } \
        { int r = t >> 3,       cl = t & 7;       q_lds[pp][r][cl] = pq0; }  \
        { int r = (t+256) >> 3, cl = (t+256) & 7; q_lds[pp][r][cl] = pq1; }  \
    } while (0)

    float acc[5][4], ee[5], qq[4];
    #pragma unroll
    for (int i = 0; i < 5; ++i) {
        ee[i] = 0.f;
        #pragma unroll
        for (int j = 0; j < 4; ++j) acc[i][j] = 0.f;
    }
    #pragma unroll
    for (int j = 0; j < 4; ++j) qq[j] = 0.f;

    LOAD_CHUNK(0);
    WRITE_CHUNK(0);
    __syncthreads();

    int p = 0;
    for (int ch = 0; ch < NCH; ++ch) {
        if (ch + 1 < NCH) LOAD_CHUNK(ch + 1);    // global prefetch (async)

        #pragma unroll
        for (int s = 0; s < KC; ++s) {
            float4 a[5], b[4];
            #pragma unroll
            for (int i = 0; i < 5; ++i) a[i] = e_lds[p][tc + 16 * i][s];
            #pragma unroll
            for (int j = 0; j < 4; ++j) b[j] = q_lds[p][tb + 16 * j][s];

            #pragma unroll
            for (int i = 0; i < 5; ++i)
                ee[i] = fmaf(a[i].x,a[i].x, fmaf(a[i].y,a[i].y,
                        fmaf(a[i].z,a[i].z, fmaf(a[i].w,a[i].w, ee[i]))));
            #pragma unroll
            for (int j = 0; j < 4; ++j)
                qq[j] = fmaf(b[j].x,b[j].x, fmaf(b[j].y,b[j].y,
                        fmaf(b[j].z,b[j].z, fmaf(b[j].w,b[j].w, qq[j]))));
            #pragma unroll
            for (int i = 0; i < 5; ++i)
                #pragma unroll
                for (int j = 0; j < 4; ++j)
                    acc[i][j] = fmaf(a[i].x,b[j].x, fmaf(a[i].y,b[j].y,
                                fmaf(a[i].z,b[j].z, fmaf(a[i].w,b[j].w, acc[i][j]))));
        }

        if (ch + 1 < NCH) {
            WRITE_CHUNK(p ^ 1);    // other buffer: no conflict with readers
            __syncthreads();       // single barrier per chunk
            p ^= 1;
        }
    }

    float einv[5], qinv[4];
    #pragma unroll
    for (int i = 0; i < 5; ++i) einv[i] = 1.f / fmaxf(sqrtf(ee[i]), EPSN);
    #pragma unroll
    for (int j = 0; j < 4; ++j) qinv[j] = 1.f / fmaxf(sqrtf(qq[j]), EPSN);

    #pragma unroll
    for (int j = 0; j < 4; ++j) {
        int b = tb + 16 * j;
        if (b < B) {
            #pragma unroll
            for (int i = 0; i < 5; ++i) {
                int c = c0 + tc + 16 * i;
                if (c < C) sims[(size_t)b * C + c] = acc[i][j] * qinv[j] * einv[i];
            }
        }
    }
    #undef WRITE_CHUNK
    #undef LOAD_CHUNK
    #undef LOAD_Q
    #undef LOAD_E
}

// ---------------------------------------------------------------------------
// Kernel 2 (topk_scan): round-8 scan, now exactly B*4 = 256 blocks (1/CU).
// Blocks (b,seg): scan C/4 of row b (8-deep batched loads) -> top-8 -> cand.
// ---------------------------------------------------------------------------
__global__ __launch_bounds__(256)
void topk_scan(const float* __restrict__ sims,
               u64* __restrict__ cand, int C, int B) {
    const int t = threadIdx.x;

    __shared__ u64 sh[256 * 8];   // 16 KB
    const int b    = blockIdx.x >> 2;
    const int seg  = blockIdx.x & 3;
    const int slen = (C + 3) >> 2;
    const int cbeg = seg * slen;
    const int cend = min(cbeg + slen, C);
    const float* row = sims + (size_t)b * C;

    u64 ls[8];
    #pragma unroll
    for (int j = 0; j < 8; ++j) ls[j] = 0ull;

    int c = cbeg + t;
    for (; c + 7 * 256 < cend; c += 8 * 256) {     // 8 independent loads first
        float v[8];
        #pragma unroll
        for (int u = 0; u < 8; ++u) v[u] = row[c + u * 256];
        #pragma unroll
        for (int u = 0; u < 8; ++u) insert8(ls, make_key(v[u], c + u * 256));
    }
    for (; c < cend; c += 256) insert8(ls, make_key(row[c], c));

    #pragma unroll
    for (int j = 0; j < 8; ++j) sh[t * 8 + j] = ls[j];
    __syncthreads();

    if (t < 64) {
        u64 m[8];
        #pragma unroll
        for (int j = 0; j < 8; ++j) m[j] = 0ull;
        for (int tt = 0; tt < 4; ++tt) {
            const u64* pp = &sh[(t * 4 + tt) * 8];
            #pragma unroll
            for (int j = 0; j < 8; ++j) {
                u64 k = pp[j];
                if (k <= m[7]) break;           // pp[] sorted descending
                m[7] = k;
                #pragma unroll
                for (int q = 7; q > 0; --q)
                    if (m[q] > m[q-1]) { u64 tmp = m[q]; m[q] = m[q-1]; m[q-1] = tmp; }
            }
        }
        for (int r = 0; r < 8; ++r) {
            u64 best = m[0];
            #pragma unroll
            for (int off = 32; off; off >>= 1) {
                u64 o = __shfl_xor(best, off, 64);
                if (o > best) best = o;
            }
            if (m[0] == best) {                 // unique owner pops
                #pragma unroll
                for (int q = 0; q < 7; ++q) m[q] = m[q+1];
                m[7] = 0ull;
            }
            if (t == 0) cand[((size_t)b * 4 + seg) * 8 + r] = best;
        }
    }
}

// ---------------------------------------------------------------------------
// Kernel 3 (gather): identical to round 8. TWO blocks per (b, j); each merges
// b's 32 segment candidates in-register -> rank-j key gives episode index AND
// score, then copies its half episode.
// ---------------------------------------------------------------------------
__global__ __launch_bounds__(256)
void gather_kernel(const float* __restrict__ episodes,    // [C][S][256]
                   const float* __restrict__ compressed,  // [C][Cs][256]
                   const void* __restrict__ is_comp,
                   const u64* __restrict__ cand,          // [B][4][8]
                   const int* __restrict__ flags,
                   float* __restrict__ out,               // [B*8][S*256]
                   float* __restrict__ scores_out,        // [B*8]
                   int S, int Cs) {
    const int bj = blockIdx.x >> 1;
    const int h  = blockIdx.x & 1;
    const int b  = bj >> 3;
    const int j  = bj & 7;

    // merge 32 candidate keys -> top-8 (sorted desc); rank j = ls[j]
    const u64* cb = cand + (size_t)b * 32;
    u64 ls[8];
    #pragma unroll
    for (int q = 0; q < 8; ++q) ls[q] = 0ull;
    #pragma unroll
    for (int i = 0; i < 32; ++i) insert8(ls, cb[i]);

    const u64 kj  = ls[j];
    const int idx = key_idx(kj);
    if (h == 0 && threadIdx.x == 0) scores_out[bj] = key_val(kj);

    const int f_off = flags[0], f_gt1 = flags[1];
    bool comp;
    if      (f_gt1) comp = ((const float*)is_comp)[idx] != 0.f;
    else if (f_off) comp = ((const unsigned char*)is_comp)[idx] != 0;
    else            comp = ((const int*)is_comp)[idx] != 0;

    const int n4   = S * H4;       // 2048
    const int c4   = Cs * H4;      // 1024
    const int half = n4 >> 1;      // 1024
    const int v0   = h * half;

    const float4* full4 = (const float4*)episodes   + (size_t)idx * n4;
    const float4* cmp4  = (const float4*)compressed + (size_t)idx * c4;
    float4* out4 = (float4*)out + (size_t)bj * n4;
    const float4 z = make_float4(0.f, 0.f, 0.f, 0.f);

    if (comp) {
        #pragma unroll 4
        for (int v = v0 + threadIdx.x; v < v0 + half; v += 256)
            out4[v] = (v < c4) ? cmp4[v] : z;
    } else {
        #pragma unroll 4
        for (int v = v0 + threadIdx.x; v < v0 + half; v += 256)
            out4[v] = full4[v];
    }
}

// ---------------------------------------------------------------------------
extern "C" void kernel_launch(void* const* d_in, const int* in_sizes, int n_in,
                              void* d_out, int out_size, void* d_ws, size_t ws_size,
                              hipStream_t stream) {
    const float* query      = (const float*)d_in[0];
    const float* episodes   = (const float*)d_in[1];
    const float* compressed = (const float*)d_in[2];
    const float* emb        = (const float*)d_in[3];
    const void*  is_comp    = d_in[4];
    // d_in[5] is k (device scalar); fixed at 8 by the problem setup.

    const int B  = in_sizes[0] / HDIM;        // 64
    const int C  = in_sizes[3] / HDIM;        // 20000
    const int S  = in_sizes[1] / (C * HDIM);  // 32
    const int Cs = in_sizes[2] / (C * HDIM);  // 16
    const int K  = 8;
    const int NT = (C + CT - 1) / CT;         // 250

    float* out        = (float*)d_out;
    float* scores_out = out + (size_t)B * K * S * HDIM;

    // scratch layout in d_ws (fully rewritten every call -> deterministic):
    float* sims    = (float*)d_ws;                             // B*C floats
    size_t simsOff = (((size_t)B * C * sizeof(float)) + 255) & ~(size_t)255;
    u64*   cand    = (u64*)((char*)d_ws + simsOff);            // B*4*8 u64
    int*   flags   = (int*)(cand + (size_t)B * 32);            // 2 ints

    sims_kernel<<<NT + 1, 256, 0, stream>>>(
        (const float4*)query, (const float4*)emb, (const u32*)is_comp,
        sims, flags, C, B, NT);
    topk_scan<<<B * 4, 256, 0, stream>>>(sims, cand, C, B);
    gather_kernel<<<B * K * 2, 256, 0, stream>>>(episodes, compressed, is_comp,
                                                 cand, flags, out, scores_out,
                                                 S, Cs);
}

// Round 14
// 54.217 us; speedup vs baseline: 2.0522x; 1.0206x over previous
//
#include <hip/hip_runtime.h>
#include <math.h>

#define HDIM 256
#define H4   64          // HDIM / 4
#define EPSN 1e-8f       // torch F.cosine_similarity norm clamp
#define CT   80          // c-tile per block -> grid = 250 blocks (no CU tail)
#define KC   8           // f4 k-steps per chunk (32 floats)
#define NCH  8           // chunks: KC*NCH = H4

typedef unsigned long long u64;
typedef unsigned int       u32;

// Monotonic (value, index) packing: larger key == better candidate under
// lax.top_k semantics (descending value, lower index wins ties).
__device__ __forceinline__ u64 make_key(float v, int idx) {
    u32 u = __float_as_uint(v);
    u ^= (u & 0x80000000u) ? 0xFFFFFFFFu : 0x80000000u;
    return ((u64)u << 32) | (u32)(~idx);
}
__device__ __forceinline__ float key_val(u64 k) {
    u32 u = (u32)(k >> 32);
    u ^= (u & 0x80000000u) ? 0x80000000u : 0xFFFFFFFFu;
    return __uint_as_float(u);
}
__device__ __forceinline__ int key_idx(u64 k) { return (int)(~(u32)k); }

__device__ __forceinline__ void insert8(u64* ls, u64 k) {
    if (k > ls[7]) {
        ls[7] = k;
        #pragma unroll
        for (int j = 7; j > 0; --j)
            if (ls[j] > ls[j-1]) { u64 tmp = ls[j]; ls[j] = ls[j-1]; ls[j-1] = tmp; }
    }
}

// ---------------------------------------------------------------------------
// Kernel 1 (sims + local top-8): main loop and score arithmetic IDENTICAL to
// round 8/13 (dbuf LDS, 5x4 reg tile, fused norms, 1 barrier/chunk).
// Epilogue v2 (fixing round-10's scatter-store bug): scores -> LDS; 4 threads
// per b scan 20 c's each -> per-(b,g) top-8; cross-g merge in LDS -> top-8
// per (b,tile); wave 0 stores 64 consecutive 64B chunks (4KB contiguous per
// tile) to cand[tile][b][8]. Eliminates the 5.1MB sims array + its re-read.
// Block NT: is_compressed layout detection (unchanged, validated r1-13).
// ---------------------------------------------------------------------------
__global__ __launch_bounds__(256)
void sims_kernel(const float4* __restrict__ q4, const float4* __restrict__ emb4,
                 const u32* __restrict__ mask4, u64* __restrict__ cand,
                 int* __restrict__ flags, int C, int B, int NT) {
    const int t = threadIdx.x;

    if (blockIdx.x == (unsigned)NT) {        // ---- mask layout detection ----
        __shared__ int red0[4], red1[4];
        int lo = 0, lg = 0;
        const int n4 = C >> 2;
        int i = t;
        for (; i + 768 < n4; i += 1024) {
            u32 v0 = mask4[i], v1 = mask4[i + 256], v2 = mask4[i + 512], v3 = mask4[i + 768];
            u32 o = v0 | v1 | v2 | v3;
            if (o & 0xFFFFFF00u) lo = 1;   // nonzero byte at offset 1..3
            if (o & 0xFEFEFEFEu) lg = 1;   // any byte value > 1
        }
        for (; i < n4; i += 256) {
            u32 v = mask4[i];
            if (v & 0xFFFFFF00u) lo = 1;
            if (v & 0xFEFEFEFEu) lg = 1;
        }
        const unsigned char* mb = (const unsigned char*)mask4;
        for (int j = (n4 << 2) + t; j < C; j += 256) {
            unsigned char v = mb[j];
            if (v > 1) lg = 1;
            if ((j & 3) != 0 && v != 0) lo = 1;
        }
        lo = __any(lo); lg = __any(lg);
        if ((t & 63) == 0) { red0[t >> 6] = lo; red1[t >> 6] = lg; }
        __syncthreads();
        if (t == 0) {
            flags[0] = red0[0] | red0[1] | red0[2] | red0[3];
            flags[1] = red1[0] | red1[1] | red1[2] | red1[3];
        }
        return;
    }

    __shared__ union {
        struct { float4 e[2][CT][KC + 1]; float4 q[2][64][KC + 1]; } st;   // 41.5 KB
        struct { float sc[64][CT + 1]; u64 sp[64][3][8]; } ep;             // 33.0 KB (disjoint members)
    } sm;

    const int c0 = blockIdx.x * CT;
    const int tc = t & 15;       // c-rows: tc + 16i, i < 5
    const int tb = t >> 4;       // b-rows: tb + 16j, j < 4
    const float4 z = make_float4(0.f, 0.f, 0.f, 0.f);

    float4 pe0, pe1, pe2, pq0, pq1;

    #define LOAD_E(idx, ch, dst) do {                                        \
        int _r = (idx) >> 3, _cl = (idx) & 7; int _gc = c0 + _r;             \
        dst = (_gc < C) ? emb4[(size_t)_gc * H4 + (ch) * KC + _cl] : z;      \
    } while (0)
    #define LOAD_Q(idx, ch, dst) do {                                        \
        int _r = (idx) >> 3, _cl = (idx) & 7;                                \
        dst = (_r < B) ? q4[(size_t)_r * H4 + (ch) * KC + _cl] : z;          \
    } while (0)
    #define LOAD_CHUNK(ch) do {                                              \
        LOAD_E(t,       ch, pe0); LOAD_E(t + 256, ch, pe1);                  \
        if (t < 128) LOAD_E(t + 512, ch, pe2);                               \
        LOAD_Q(t,       ch, pq0); LOAD_Q(t + 256, ch, pq1);                  \
    } while (0)
    #define WRITE_CHUNK(pp) do {                                             \
        { int r = t >> 3,       cl = t & 7;       sm.st.e[pp][r][cl] = pe0; }\
        { int r = (t+256) >> 3, cl = (t+256) & 7; sm.st.e[pp][r][cl] = pe1; }\
        if (t < 128) { int r = (t+512) >> 3, cl = (t+512) & 7; sm.st.e[pp][r][cl] = pe2; } \
        { int r = t >> 3,       cl = t & 7;       sm.st.q[pp][r][cl] = pq0; }\
        { int r = (t+256) >> 3, cl = (t+256) & 7; sm.st.q[pp][r][cl] = pq1; }\
    } while (0)

    float acc[5][4], ee[5], qq[4];
    #pragma unroll
    for (int i = 0; i < 5; ++i) {
        ee[i] = 0.f;
        #pragma unroll
        for (int j = 0; j < 4; ++j) acc[i][j] = 0.f;
    }
    #pragma unroll
    for (int j = 0; j < 4; ++j) qq[j] = 0.f;

    LOAD_CHUNK(0);
    WRITE_CHUNK(0);
    __syncthreads();

    int p = 0;
    for (int ch = 0; ch < NCH; ++ch) {
        if (ch + 1 < NCH) LOAD_CHUNK(ch + 1);    // global prefetch (async)

        #pragma unroll
        for (int s = 0; s < KC; ++s) {
            float4 a[5], b[4];
            #pragma unroll
            for (int i = 0; i < 5; ++i) a[i] = sm.st.e[p][tc + 16 * i][s];
            #pragma unroll
            for (int j = 0; j < 4; ++j) b[j] = sm.st.q[p][tb + 16 * j][s];

            #pragma unroll
            for (int i = 0; i < 5; ++i)
                ee[i] = fmaf(a[i].x,a[i].x, fmaf(a[i].y,a[i].y,
                        fmaf(a[i].z,a[i].z, fmaf(a[i].w,a[i].w, ee[i]))));
            #pragma unroll
            for (int j = 0; j < 4; ++j)
                qq[j] = fmaf(b[j].x,b[j].x, fmaf(b[j].y,b[j].y,
                        fmaf(b[j].z,b[j].z, fmaf(b[j].w,b[j].w, qq[j]))));
            #pragma unroll
            for (int i = 0; i < 5; ++i)
                #pragma unroll
                for (int j = 0; j < 4; ++j)
                    acc[i][j] = fmaf(a[i].x,b[j].x, fmaf(a[i].y,b[j].y,
                                fmaf(a[i].z,b[j].z, fmaf(a[i].w,b[j].w, acc[i][j]))));
        }

        if (ch + 1 < NCH) {
            WRITE_CHUNK(p ^ 1);    // other buffer: no conflict with readers
            __syncthreads();       // single barrier per chunk
            p ^= 1;
        }
    }

    float einv[5], qinv[4];
    #pragma unroll
    for (int i = 0; i < 5; ++i) einv[i] = 1.f / fmaxf(sqrtf(ee[i]), EPSN);
    #pragma unroll
    for (int j = 0; j < 4; ++j) qinv[j] = 1.f / fmaxf(sqrtf(qq[j]), EPSN);

    // ---- epilogue v2: scores -> LDS, per-(b,tile) top-8, contiguous store --
    __syncthreads();               // all waves done reading sm.st
    #pragma unroll
    for (int j = 0; j < 4; ++j) {
        int b = tb + 16 * j;
        if (b < B) {
            #pragma unroll
            for (int i = 0; i < 5; ++i)
                sm.ep.sc[b][tc + 16 * i] = acc[i][j] * qinv[j] * einv[i];
        }
    }
    __syncthreads();

    const int sb = t & 63;         // b
    const int g  = t >> 6;         // c-group (20 c's each)
    u64 ls[8];
    #pragma unroll
    for (int j = 0; j < 8; ++j) ls[j] = 0ull;
    if (sb < B) {
        #pragma unroll
        for (int i2 = 0; i2 < 20; ++i2) {
            int cl = g * 20 + i2;
            int c  = c0 + cl;
            if (c < C) insert8(ls, make_key(sm.ep.sc[sb][cl], c));
        }
    }
    if (g != 0) {                  // sp disjoint from sc: no alias hazard
        #pragma unroll
        for (int r = 0; r < 8; ++r) sm.ep.sp[sb][g - 1][r] = ls[r];
    }
    __syncthreads();
    if (g == 0) {                  // wave 0: merge 4x8 -> 8, contiguous store
        #pragma unroll
        for (int gg = 0; gg < 3; ++gg)
            #pragma unroll
            for (int r = 0; r < 8; ++r) {
                u64 k = sm.ep.sp[sb][gg][r];
                insert8(ls, k);
            }
        u64* dst = cand + (((size_t)blockIdx.x * 64) + sb) * 8;   // 64B/lane, 4KB/wave
        #pragma unroll
        for (int r = 0; r < 8; ++r) dst[r] = ls[r];
    }
    #undef WRITE_CHUNK
    #undef LOAD_CHUNK
    #undef LOAD_Q
    #undef LOAD_E
}

// ---------------------------------------------------------------------------
// Kernel 2 (merge): B blocks. Block b: thread t reads tile t's 8 sorted keys
// for b (64B contiguous per thread, one latency round for all 250), local
// top-8 with early break, then the trusted block merge -> scores + top_idx.
// ---------------------------------------------------------------------------
__global__ __launch_bounds__(256)
void merge_kernel(const u64* __restrict__ cand,
                  float* __restrict__ scores_out, int* __restrict__ top_idx,
                  int B, int NT) {
    __shared__ u64 sh[256 * 8];   // 16 KB
    const int b = blockIdx.x, t = threadIdx.x;

    u64 ls[8];
    #pragma unroll
    for (int j = 0; j < 8; ++j) ls[j] = 0ull;

    for (int tile = t; tile < NT; tile += 256) {
        const u64* pp = cand + (((size_t)tile * 64) + b) * 8;
        #pragma unroll
        for (int r = 0; r < 8; ++r) {
            u64 k = pp[r];
            if (k <= ls[7]) break;          // pp[] sorted descending
            ls[7] = k;
            #pragma unroll
            for (int q = 7; q > 0; --q)
                if (ls[q] > ls[q-1]) { u64 tmp = ls[q]; ls[q] = ls[q-1]; ls[q-1] = tmp; }
        }
    }

    #pragma unroll
    for (int j = 0; j < 8; ++j) sh[t * 8 + j] = ls[j];
    __syncthreads();

    if (t < 64) {
        u64 m[8];
        #pragma unroll
        for (int j = 0; j < 8; ++j) m[j] = 0ull;
        for (int tt = 0; tt < 4; ++tt) {
            const u64* pp = &sh[(t * 4 + tt) * 8];
            #pragma unroll
            for (int j = 0; j < 8; ++j) {
                u64 k = pp[j];
                if (k <= m[7]) break;           // pp[] sorted descending
                m[7] = k;
                #pragma unroll
                for (int q = 7; q > 0; --q)
                    if (m[q] > m[q-1]) { u64 tmp = m[q]; m[q] = m[q-1]; m[q-1] = tmp; }
            }
        }
        for (int r = 0; r < 8; ++r) {
            u64 best = m[0];
            #pragma unroll
            for (int off = 32; off; off >>= 1) {
                u64 o = __shfl_xor(best, off, 64);
                if (o > best) best = o;
            }
            if (m[0] == best) {                 // unique owner pops
                #pragma unroll
                for (int q = 0; q < 7; ++q) m[q] = m[q+1];
                m[7] = 0ull;
            }
            if (t == 0) {
                scores_out[b * 8 + r] = key_val(best);
                top_idx[b * 8 + r]    = key_idx(best);
            }
        }
    }
}

// ---------------------------------------------------------------------------
// Kernel 3 (gather): TWO blocks per (b, j): half episode each, float4 copy.
// ---------------------------------------------------------------------------
__global__ __launch_bounds__(256)
void gather_kernel(const float* __restrict__ episodes,    // [C][S][256]
                   const float* __restrict__ compressed,  // [C][Cs][256]
                   const void* __restrict__ is_comp,
                   const int* __restrict__ top_idx,       // [B*8]
                   const int* __restrict__ flags,
                   float* __restrict__ out,               // [B*8][S*256]
                   int S, int Cs) {
    const int bj  = blockIdx.x >> 1;
    const int h   = blockIdx.x & 1;
    const int idx = top_idx[bj];
    const int f_off = flags[0], f_gt1 = flags[1];

    bool comp;
    if      (f_gt1) comp = ((const float*)is_comp)[idx] != 0.f;
    else if (f_off) comp = ((const unsigned char*)is_comp)[idx] != 0;
    else            comp = ((const int*)is_comp)[idx] != 0;

    const int n4   = S * H4;       // 2048
    const int c4   = Cs * H4;      // 1024
    const int half = n4 >> 1;      // 1024
    const int v0   = h * half;

    const float4* full4 = (const float4*)episodes   + (size_t)idx * n4;
    const float4* cmp4  = (const float4*)compressed + (size_t)idx * c4;
    float4* out4 = (float4*)out + (size_t)bj * n4;
    const float4 z = make_float4(0.f, 0.f, 0.f, 0.f);

    if (comp) {
        #pragma unroll 4
        for (int v = v0 + threadIdx.x; v < v0 + half; v += 256)
            out4[v] = (v < c4) ? cmp4[v] : z;
    } else {
        #pragma unroll 4
        for (int v = v0 + threadIdx.x; v < v0 + half; v += 256)
            out4[v] = full4[v];
    }
}

// ---------------------------------------------------------------------------
extern "C" void kernel_launch(void* const* d_in, const int* in_sizes, int n_in,
                              void* d_out, int out_size, void* d_ws, size_t ws_size,
                              hipStream_t stream) {
    const float* query      = (const float*)d_in[0];
    const float* episodes   = (const float*)d_in[1];
    const float* compressed = (const float*)d_in[2];
    const float* emb        = (const float*)d_in[3];
    const void*  is_comp    = d_in[4];
    // d_in[5] is k (device scalar); fixed at 8 by the problem setup.

    const int B  = in_sizes[0] / HDIM;        // 64
    const int C  = in_sizes[3] / HDIM;        // 20000
    const int S  = in_sizes[1] / (C * HDIM);  // 32
    const int Cs = in_sizes[2] / (C * HDIM);  // 16
    const int K  = 8;
    const int NT = (C + CT - 1) / CT;         // 250

    float* out        = (float*)d_out;
    float* scores_out = out + (size_t)B * K * S * HDIM;

    // scratch layout in d_ws (fully rewritten every call -> deterministic):
    u64*  cand    = (u64*)d_ws;                          // NT*64*8 u64 = 1.0 MB
    int*  top_idx = (int*)(cand + (size_t)NT * 64 * 8);  // B*K ints
    int*  flags   = top_idx + B * K;                     // 2 ints

    sims_kernel<<<NT + 1, 256, 0, stream>>>(
        (const float4*)query, (const float4*)emb, (const u32*)is_comp,
        cand, flags, C, B, NT);
    merge_kernel<<<B, 256, 0, stream>>>(cand, scores_out, top_idx, B, NT);
    gather_kernel<<<B * K * 2, 256, 0, stream>>>(episodes, compressed, is_comp,
                                                 top_idx, flags, out, S, Cs);
}

// Round 15
// 46.520 us; speedup vs baseline: 2.3917x; 1.1654x over previous
//
#include <hip/hip_runtime.h>
#include <math.h>

#define HDIM 256
#define H4   64          // HDIM / 4
#define EPSN 1e-8f       // torch F.cosine_similarity norm clamp
#define CT   80          // c-tile per block -> grid = 250 blocks (no CU tail)
#define KC   8           // f4 k-steps per chunk (32 floats)
#define NCH  8           // chunks: KC*NCH = H4
#define LDK  40          // LDS row stride in bf16 (80B: 16B-aligned, bank-balanced)

typedef unsigned long long u64;
typedef unsigned int       u32;
typedef __attribute__((ext_vector_type(8))) __bf16 bf16x8;
typedef __attribute__((ext_vector_type(4))) __bf16 bf16x4;
typedef __attribute__((ext_vector_type(4))) float  f32x4;

// Monotonic (value, index) packing: larger key == better candidate under
// lax.top_k semantics (descending value, lower index wins ties).
__device__ __forceinline__ u64 make_key(float v, int idx) {
    u32 u = __float_as_uint(v);
    u ^= (u & 0x80000000u) ? 0xFFFFFFFFu : 0x80000000u;
    return ((u64)u << 32) | (u32)(~idx);
}
__device__ __forceinline__ float key_val(u64 k) {
    u32 u = (u32)(k >> 32);
    u ^= (u & 0x80000000u) ? 0x80000000u : 0xFFFFFFFFu;
    return __uint_as_float(u);
}
__device__ __forceinline__ int key_idx(u64 k) { return (int)(~(u32)k); }

__device__ __forceinline__ void insert8(u64* ls, u64 k) {
    if (k > ls[7]) {
        ls[7] = k;
        #pragma unroll
        for (int j = 7; j > 0; --j)
            if (ls[j] > ls[j-1]) { u64 tmp = ls[j]; ls[j] = ls[j-1]; ls[j-1] = tmp; }
    }
}

// ---------------------------------------------------------------------------
// Kernel 1 (sims via split-bf16 MFMA + local top-8).
// Staging/dbuf/barrier structure identical to R8/R14; compute replaced:
// fp32 -> (hi,lo) bf16 at staging; per K-chunk of 32:
//   acc += mfma16x16x32(ah,bh) + mfma(ah,bl) + mfma(al,bh)
// A = q (M=16 b rows/wave), B = e^T (N=16 c cols/subtile, 5 subtiles).
// Fragment mapping (m89/m91-verified): A lane row = l&15, k-grp = l>>4;
// D: col(c) = l&15, row(b) = (l>>4)*4 + reg. Norms from hi+lo reconstruction
// (error ~2^-17) reduced via shfl_xor(16,32), routed through LDS.
// Epilogue top-8 + contiguous cand store: identical to R14.
// Block NT: is_compressed layout detection (unchanged, validated r1-14).
// ---------------------------------------------------------------------------
__global__ __launch_bounds__(256)
void sims_kernel(const float4* __restrict__ q4, const float4* __restrict__ emb4,
                 const u32* __restrict__ mask4, u64* __restrict__ cand,
                 int* __restrict__ flags, int C, int B, int NT) {
    const int t = threadIdx.x;

    if (blockIdx.x == (unsigned)NT) {        // ---- mask layout detection ----
        __shared__ int red0[4], red1[4];
        int lo = 0, lg = 0;
        const int n4 = C >> 2;
        int i = t;
        for (; i + 768 < n4; i += 1024) {
            u32 v0 = mask4[i], v1 = mask4[i + 256], v2 = mask4[i + 512], v3 = mask4[i + 768];
            u32 o = v0 | v1 | v2 | v3;
            if (o & 0xFFFFFF00u) lo = 1;   // nonzero byte at offset 1..3
            if (o & 0xFEFEFEFEu) lg = 1;   // any byte value > 1
        }
        for (; i < n4; i += 256) {
            u32 v = mask4[i];
            if (v & 0xFFFFFF00u) lo = 1;
            if (v & 0xFEFEFEFEu) lg = 1;
        }
        const unsigned char* mb = (const unsigned char*)mask4;
        for (int j = (n4 << 2) + t; j < C; j += 256) {
            unsigned char v = mb[j];
            if (v > 1) lg = 1;
            if ((j & 3) != 0 && v != 0) lo = 1;
        }
        lo = __any(lo); lg = __any(lg);
        if ((t & 63) == 0) { red0[t >> 6] = lo; red1[t >> 6] = lg; }
        __syncthreads();
        if (t == 0) {
            flags[0] = red0[0] | red0[1] | red0[2] | red0[3];
            flags[1] = red1[0] | red1[1] | red1[2] | red1[3];
        }
        return;
    }

    __shared__ union {
        struct {                              // double-buffered bf16 staging
            __bf16 eh[2][CT][LDK];            // 12.8 KB
            __bf16 el[2][CT][LDK];            // 12.8 KB
            __bf16 qh[2][64][LDK];            // 10.24 KB
            __bf16 ql[2][64][LDK];            // 10.24 KB  (total 46.08 KB)
        } st;
        struct { float sc[64][CT + 1]; u64 sp[64][3][8];
                 float qn[64]; float en[CT]; } ep;   // 33.6 KB, members disjoint
    } sm;

    const int c0   = blockIdx.x * CT;
    const int lane = t & 63;
    const int w    = t >> 6;          // wave = b-quadrant (16 b's)
    const int mrow = lane & 15;
    const int kg   = lane >> 4;       // k-group within fragment
    const float4 z = make_float4(0.f, 0.f, 0.f, 0.f);

    float4 pe0, pe1, pe2, pq0, pq1;

    #define LOAD_E(idx, ch, dst) do {                                        \
        int _r = (idx) >> 3, _cl = (idx) & 7; int _gc = c0 + _r;             \
        dst = (_gc < C) ? emb4[(size_t)_gc * H4 + (ch) * KC + _cl] : z;      \
    } while (0)
    #define LOAD_Q(idx, ch, dst) do {                                        \
        int _r = (idx) >> 3, _cl = (idx) & 7;                                \
        dst = (_r < B) ? q4[(size_t)_r * H4 + (ch) * KC + _cl] : z;          \
    } while (0)
    #define LOAD_CHUNK(ch) do {                                              \
        LOAD_E(t,       ch, pe0); LOAD_E(t + 256, ch, pe1);                  \
        if (t < 128) LOAD_E(t + 512, ch, pe2);                               \
        LOAD_Q(t,       ch, pq0); LOAD_Q(t + 256, ch, pq1);                  \
    } while (0)
    // fp32 -> (hi,lo) bf16 split; RNE casts, deterministic
    #define CVTW(v, HI, LO, r, k0) do {                                      \
        bf16x4 _h, _l;                                                       \
        _h.x = (__bf16)v.x; _h.y = (__bf16)v.y;                              \
        _h.z = (__bf16)v.z; _h.w = (__bf16)v.w;                              \
        float _rx = v.x - (float)_h.x, _ry = v.y - (float)_h.y;              \
        float _rz = v.z - (float)_h.z, _rw = v.w - (float)_h.w;              \
        _l.x = (__bf16)_rx; _l.y = (__bf16)_ry;                              \
        _l.z = (__bf16)_rz; _l.w = (__bf16)_rw;                              \
        *(bf16x4*)&HI[r][k0] = _h; *(bf16x4*)&LO[r][k0] = _l;                \
    } while (0)
    #define WRITE_CHUNK(pp) do {                                             \
        { int r = t >> 3,       k0 = (t & 7) * 4;                            \
          CVTW(pe0, sm.st.eh[pp], sm.st.el[pp], r, k0); }                    \
        { int r = (t+256) >> 3, k0 = (t & 7) * 4;                            \
          CVTW(pe1, sm.st.eh[pp], sm.st.el[pp], r, k0); }                    \
        if (t < 128) { int r = (t+512) >> 3, k0 = (t & 7) * 4;               \
          CVTW(pe2, sm.st.eh[pp], sm.st.el[pp], r, k0); }                    \
        { int r = t >> 3,       k0 = (t & 7) * 4;                            \
          CVTW(pq0, sm.st.qh[pp], sm.st.ql[pp], r, k0); }                    \
        { int r = (t+256) >> 3, k0 = (t & 7) * 4;                            \
          CVTW(pq1, sm.st.qh[pp], sm.st.ql[pp], r, k0); }                    \
    } while (0)

    f32x4 acc[5];
    #pragma unroll
    for (int s = 0; s < 5; ++s) acc[s] = (f32x4){0.f, 0.f, 0.f, 0.f};
    float qpart = 0.f;
    float epart[5] = {0.f, 0.f, 0.f, 0.f, 0.f};

    LOAD_CHUNK(0);
    WRITE_CHUNK(0);
    __syncthreads();

    int p = 0;
    for (int ch = 0; ch < NCH; ++ch) {
        if (ch + 1 < NCH) LOAD_CHUNK(ch + 1);    // global prefetch (async)

        bf16x8 ah = *(const bf16x8*)&sm.st.qh[p][w * 16 + mrow][kg * 8];
        bf16x8 al = *(const bf16x8*)&sm.st.ql[p][w * 16 + mrow][kg * 8];
        #pragma unroll
        for (int i = 0; i < 8; ++i) {            // q-norm partial (hi+lo)
            float x = (float)ah[i] + (float)al[i];
            qpart = fmaf(x, x, qpart);
        }
        #pragma unroll
        for (int s = 0; s < 5; ++s) {
            bf16x8 bh = *(const bf16x8*)&sm.st.eh[p][s * 16 + mrow][kg * 8];
            bf16x8 bl = *(const bf16x8*)&sm.st.el[p][s * 16 + mrow][kg * 8];
            if (w == 0) {                        // e-norm partial (wave 0)
                #pragma unroll
                for (int i = 0; i < 8; ++i) {
                    float x = (float)bh[i] + (float)bl[i];
                    epart[s] = fmaf(x, x, epart[s]);
                }
            }
            acc[s] = __builtin_amdgcn_mfma_f32_16x16x32_bf16(ah, bh, acc[s], 0, 0, 0);
            acc[s] = __builtin_amdgcn_mfma_f32_16x16x32_bf16(ah, bl, acc[s], 0, 0, 0);
            acc[s] = __builtin_amdgcn_mfma_f32_16x16x32_bf16(al, bh, acc[s], 0, 0, 0);
        }

        if (ch + 1 < NCH) {
            WRITE_CHUNK(p ^ 1);    // other buffer: no conflict with readers
            __syncthreads();       // single barrier per chunk
            p ^= 1;
        }
    }

    // ---- norms: reduce across k-groups, route through LDS ----
    __syncthreads();               // all waves done reading sm.st
    qpart += __shfl_xor(qpart, 16, 64);
    qpart += __shfl_xor(qpart, 32, 64);
    if (kg == 0) sm.ep.qn[w * 16 + mrow] = 1.f / fmaxf(sqrtf(qpart), EPSN);
    if (w == 0) {
        #pragma unroll
        for (int s = 0; s < 5; ++s) {
            float e = epart[s];
            e += __shfl_xor(e, 16, 64);
            e += __shfl_xor(e, 32, 64);
            if (kg == 0) sm.ep.en[s * 16 + mrow] = 1.f / fmaxf(sqrtf(e), EPSN);
        }
    }
    __syncthreads();

    // ---- scores -> LDS: lane holds D[b = w*16+kg*4+r][c = s*16+mrow] ----
    float qv[4];
    #pragma unroll
    for (int r = 0; r < 4; ++r) qv[r] = sm.ep.qn[w * 16 + kg * 4 + r];
    #pragma unroll
    for (int s = 0; s < 5; ++s) {
        float ev = sm.ep.en[s * 16 + mrow];
        #pragma unroll
        for (int r = 0; r < 4; ++r)
            sm.ep.sc[w * 16 + kg * 4 + r][s * 16 + mrow] = acc[s][r] * qv[r] * ev;
    }
    __syncthreads();

    // ---- per-(b,tile) top-8 + contiguous store (identical to R14) ----
    const int sb = t & 63;         // b
    const int g  = t >> 6;         // c-group (20 c's each)
    u64 ls[8];
    #pragma unroll
    for (int j = 0; j < 8; ++j) ls[j] = 0ull;
    if (sb < B) {
        #pragma unroll
        for (int i2 = 0; i2 < 20; ++i2) {
            int cl = g * 20 + i2;
            int c  = c0 + cl;
            if (c < C) insert8(ls, make_key(sm.ep.sc[sb][cl], c));
        }
    }
    if (g != 0) {                  // sp disjoint from sc: no alias hazard
        #pragma unroll
        for (int r = 0; r < 8; ++r) sm.ep.sp[sb][g - 1][r] = ls[r];
    }
    __syncthreads();
    if (g == 0) {                  // wave 0: merge 4x8 -> 8, contiguous store
        #pragma unroll
        for (int gg = 0; gg < 3; ++gg)
            #pragma unroll
            for (int r = 0; r < 8; ++r) insert8(ls, sm.ep.sp[sb][gg][r]);
        u64* dst = cand + (((size_t)blockIdx.x * 64) + sb) * 8;
        #pragma unroll
        for (int r = 0; r < 8; ++r) dst[r] = ls[r];
    }
    #undef WRITE_CHUNK
    #undef CVTW
    #undef LOAD_CHUNK
    #undef LOAD_Q
    #undef LOAD_E
}

// ---------------------------------------------------------------------------
// Kernel 2 (merge): identical to round 14.
// ---------------------------------------------------------------------------
__global__ __launch_bounds__(256)
void merge_kernel(const u64* __restrict__ cand,
                  float* __restrict__ scores_out, int* __restrict__ top_idx,
                  int B, int NT) {
    __shared__ u64 sh[256 * 8];   // 16 KB
    const int b = blockIdx.x, t = threadIdx.x;

    u64 ls[8];
    #pragma unroll
    for (int j = 0; j < 8; ++j) ls[j] = 0ull;

    for (int tile = t; tile < NT; tile += 256) {
        const u64* pp = cand + (((size_t)tile * 64) + b) * 8;
        #pragma unroll
        for (int r = 0; r < 8; ++r) {
            u64 k = pp[r];
            if (k <= ls[7]) break;          // pp[] sorted descending
            ls[7] = k;
            #pragma unroll
            for (int q = 7; q > 0; --q)
                if (ls[q] > ls[q-1]) { u64 tmp = ls[q]; ls[q] = ls[q-1]; ls[q-1] = tmp; }
        }
    }

    #pragma unroll
    for (int j = 0; j < 8; ++j) sh[t * 8 + j] = ls[j];
    __syncthreads();

    if (t < 64) {
        u64 m[8];
        #pragma unroll
        for (int j = 0; j < 8; ++j) m[j] = 0ull;
        for (int tt = 0; tt < 4; ++tt) {
            const u64* pp = &sh[(t * 4 + tt) * 8];
            #pragma unroll
            for (int j = 0; j < 8; ++j) {
                u64 k = pp[j];
                if (k <= m[7]) break;           // pp[] sorted descending
                m[7] = k;
                #pragma unroll
                for (int q = 7; q > 0; --q)
                    if (m[q] > m[q-1]) { u64 tmp = m[q]; m[q] = m[q-1]; m[q-1] = tmp; }
            }
        }
        for (int r = 0; r < 8; ++r) {
            u64 best = m[0];
            #pragma unroll
            for (int off = 32; off; off >>= 1) {
                u64 o = __shfl_xor(best, off, 64);
                if (o > best) best = o;
            }
            if (m[0] == best) {                 // unique owner pops
                #pragma unroll
                for (int q = 0; q < 7; ++q) m[q] = m[q+1];
                m[7] = 0ull;
            }
            if (t == 0) {
                scores_out[b * 8 + r] = key_val(best);
                top_idx[b * 8 + r]    = key_idx(best);
            }
        }
    }
}

// ---------------------------------------------------------------------------
// Kernel 3 (gather): identical to round 14.
// ---------------------------------------------------------------------------
__global__ __launch_bounds__(256)
void gather_kernel(const float* __restrict__ episodes,    // [C][S][256]
                   const float* __restrict__ compressed,  // [C][Cs][256]
                   const void* __restrict__ is_comp,
                   const int* __restrict__ top_idx,       // [B*8]
                   const int* __restrict__ flags,
                   float* __restrict__ out,               // [B*8][S*256]
                   int S, int Cs) {
    const int bj  = blockIdx.x >> 1;
    const int h   = blockIdx.x & 1;
    const int idx = top_idx[bj];
    const int f_off = flags[0], f_gt1 = flags[1];

    bool comp;
    if      (f_gt1) comp = ((const float*)is_comp)[idx] != 0.f;
    else if (f_off) comp = ((const unsigned char*)is_comp)[idx] != 0;
    else            comp = ((const int*)is_comp)[idx] != 0;

    const int n4   = S * H4;       // 2048
    const int c4   = Cs * H4;      // 1024
    const int half = n4 >> 1;      // 1024
    const int v0   = h * half;

    const float4* full4 = (const float4*)episodes   + (size_t)idx * n4;
    const float4* cmp4  = (const float4*)compressed + (size_t)idx * c4;
    float4* out4 = (float4*)out + (size_t)bj * n4;
    const float4 z = make_float4(0.f, 0.f, 0.f, 0.f);

    if (comp) {
        #pragma unroll 4
        for (int v = v0 + threadIdx.x; v < v0 + half; v += 256)
            out4[v] = (v < c4) ? cmp4[v] : z;
    } else {
        #pragma unroll 4
        for (int v = v0 + threadIdx.x; v < v0 + half; v += 256)
            out4[v] = full4[v];
    }
}

// ---------------------------------------------------------------------------
extern "C" void kernel_launch(void* const* d_in, const int* in_sizes, int n_in,
                              void* d_out, int out_size, void* d_ws, size_t ws_size,
                              hipStream_t stream) {
    const float* query      = (const float*)d_in[0];
    const float* episodes   = (const float*)d_in[1];
    const float* compressed = (const float*)d_in[2];
    const float* emb        = (const float*)d_in[3];
    const void*  is_comp    = d_in[4];
    // d_in[5] is k (device scalar); fixed at 8 by the problem setup.

    const int B  = in_sizes[0] / HDIM;        // 64
    const int C  = in_sizes[3] / HDIM;        // 20000
    const int S  = in_sizes[1] / (C * HDIM);  // 32
    const int Cs = in_sizes[2] / (C * HDIM);  // 16
    const int K  = 8;
    const int NT = (C + CT - 1) / CT;         // 250

    float* out        = (float*)d_out;
    float* scores_out = out + (size_t)B * K * S * HDIM;

    // scratch layout in d_ws (fully rewritten every call -> deterministic):
    u64*  cand    = (u64*)d_ws;                          // NT*64*8 u64 = 1.0 MB
    int*  top_idx = (int*)(cand + (size_t)NT * 64 * 8);  // B*K ints
    int*  flags   = top_idx + B * K;                     // 2 ints

    sims_kernel<<<NT + 1, 256, 0, stream>>>(
        (const float4*)query, (const float4*)emb, (const u32*)is_comp,
        cand, flags, C, B, NT);
    merge_kernel<<<B, 256, 0, stream>>>(cand, scores_out, top_idx, B, NT);
    gather_kernel<<<B * K * 2, 256, 0, stream>>>(episodes, compressed, is_comp,
                                                 top_idx, flags, out, S, Cs);
}

// Round 16
// 46.452 us; speedup vs baseline: 2.3952x; 1.0015x over previous
//
#include <hip/hip_runtime.h>
#include <math.h>

#define HDIM 256
#define H4   64          // HDIM / 4
#define EPSN 1e-8f       // torch F.cosine_similarity norm clamp
#define CT   128         // c-tile per block = 8 waves x 16-c subtiles; NT=157
#define KC   8           // f4 k-steps per chunk (32 floats)
#define NCH  8           // chunks: KC*NCH = H4
#define QSTR 264         // q LDS row stride in bf16 (528B: 16B-aligned, 2-way banks)

typedef unsigned long long u64;
typedef unsigned int       u32;
typedef __attribute__((ext_vector_type(8))) __bf16 bf16x8;
typedef __attribute__((ext_vector_type(4))) __bf16 bf16x4;
typedef __attribute__((ext_vector_type(4))) float  f32x4;

// Monotonic (value, index) packing: larger key == better candidate under
// lax.top_k semantics (descending value, lower index wins ties).
__device__ __forceinline__ u64 make_key(float v, int idx) {
    u32 u = __float_as_uint(v);
    u ^= (u & 0x80000000u) ? 0xFFFFFFFFu : 0x80000000u;
    return ((u64)u << 32) | (u32)(~idx);
}
__device__ __forceinline__ float key_val(u64 k) {
    u32 u = (u32)(k >> 32);
    u ^= (u & 0x80000000u) ? 0x80000000u : 0xFFFFFFFFu;
    return __uint_as_float(u);
}
__device__ __forceinline__ int key_idx(u64 k) { return (int)(~(u32)k); }

__device__ __forceinline__ void insert8(u64* ls, u64 k) {
    if (k > ls[7]) {
        ls[7] = k;
        #pragma unroll
        for (int j = 7; j > 0; --j)
            if (ls[j] > ls[j-1]) { u64 tmp = ls[j]; ls[j] = ls[j-1]; ls[j-1] = tmp; }
    }
}

// ---------------------------------------------------------------------------
// Kernel 1 (sims, zero-barrier K-loop):
//  - q staged ONCE to LDS as hi/lo bf16 (read-only thereafter); q-norms fused
//    into the staging pass (recon hi+lo, 8-thread shfl reduce).
//  - K-loop: NO barriers. Wave w owns c-subtile w (16 c's); each lane streams
//    its own e row from GLOBAL (fp32, 2-chunk register prefetch, each element
//    read exactly once on the whole chip), converts to hi/lo bf16 in-reg,
//    reads 4 q A-fragments from LDS, 12 mfma_16x16x32_bf16 per chunk
//    (3-MFMA split scheme identical to R15: ah*bh + ah*bl + al*bh).
//  - D mapping (R15-verified): b = m*16 + kg*4 + reg, c = w*16 + (lane&15).
//  - Epilogue top-8 + contiguous cand store as R14/R15 (8 groups x 16 c).
// Block NT: is_compressed layout detection (512-thread variant).
// ---------------------------------------------------------------------------
__global__ __launch_bounds__(512)
void sims_kernel(const float4* __restrict__ q4, const float4* __restrict__ emb4,
                 const u32* __restrict__ mask4, u64* __restrict__ cand,
                 int* __restrict__ flags, int C, int B, int NT) {
    const int t = threadIdx.x;

    if (blockIdx.x == (unsigned)NT) {        // ---- mask layout detection ----
        __shared__ int red0[8], red1[8];
        int lo = 0, lg = 0;
        const int n4 = C >> 2;
        int i = t;
        for (; i + 1536 < n4; i += 2048) {
            u32 v0 = mask4[i], v1 = mask4[i + 512], v2 = mask4[i + 1024], v3 = mask4[i + 1536];
            u32 o = v0 | v1 | v2 | v3;
            if (o & 0xFFFFFF00u) lo = 1;   // nonzero byte at offset 1..3
            if (o & 0xFEFEFEFEu) lg = 1;   // any byte value > 1
        }
        for (; i < n4; i += 512) {
            u32 v = mask4[i];
            if (v & 0xFFFFFF00u) lo = 1;
            if (v & 0xFEFEFEFEu) lg = 1;
        }
        const unsigned char* mb = (const unsigned char*)mask4;
        for (int j = (n4 << 2) + t; j < C; j += 512) {
            unsigned char v = mb[j];
            if (v > 1) lg = 1;
            if ((j & 3) != 0 && v != 0) lo = 1;
        }
        lo = __any(lo); lg = __any(lg);
        if ((t & 63) == 0) { red0[t >> 6] = lo; red1[t >> 6] = lg; }
        __syncthreads();
        if (t == 0) {
            int a0 = 0, a1 = 0;
            #pragma unroll
            for (int r = 0; r < 8; ++r) { a0 |= red0[r]; a1 |= red1[r]; }
            flags[0] = a0; flags[1] = a1;
        }
        return;
    }

    __shared__ union {
        struct { __bf16 qh[64][QSTR]; __bf16 ql[64][QSTR]; } st;   // 67.6 KB
        struct { float sc[64][CT + 1]; u64 sp[64][7][8]; } ep;     // 61.7 KB
    } sm;
    __shared__ float qn[64];
    __shared__ float en[CT];

    const int c0   = blockIdx.x * CT;
    const int lane = t & 63;
    const int w    = t >> 6;          // wave id = c-subtile
    const int mrow = lane & 15;
    const int kg   = lane >> 4;       // k-group within fragment
    const float4 z = make_float4(0.f, 0.f, 0.f, 0.f);

    // ---- issue e-chunk 0/1 loads first (HBM latency overlaps q staging) ----
    const int  erow = c0 + w * 16 + mrow;
    const bool ev   = erow < C;
    const float4* erp = emb4 + (size_t)erow * H4 + kg * 2;
    float4 cur0 = ev ? erp[0] : z;
    float4 cur1 = ev ? erp[1] : z;
    float4 nxt0 = ev ? erp[KC]     : z;
    float4 nxt1 = ev ? erp[KC + 1] : z;

    // ---- stage q once as hi/lo bf16; q-norms fused (recon, 8-thread reduce) --
    {
        const int r  = t >> 3;         // q row 0..63
        const int c8 = (t & 7) * 8;    // f4 base within row
        float qp = 0.f;
        #pragma unroll
        for (int i = 0; i < 8; ++i) {
            float4 v = (r < B) ? q4[(size_t)r * H4 + c8 + i] : z;
            bf16x4 h, l;
            h.x = (__bf16)v.x; h.y = (__bf16)v.y; h.z = (__bf16)v.z; h.w = (__bf16)v.w;
            l.x = (__bf16)(v.x - (float)h.x); l.y = (__bf16)(v.y - (float)h.y);
            l.z = (__bf16)(v.z - (float)h.z); l.w = (__bf16)(v.w - (float)h.w);
            *(bf16x4*)&sm.st.qh[r][(c8 + i) * 4] = h;
            *(bf16x4*)&sm.st.ql[r][(c8 + i) * 4] = l;
            float x0 = (float)h.x + (float)l.x, x1 = (float)h.y + (float)l.y;
            float x2 = (float)h.z + (float)l.z, x3 = (float)h.w + (float)l.w;
            qp = fmaf(x0, x0, fmaf(x1, x1, fmaf(x2, x2, fmaf(x3, x3, qp))));
        }
        qp += __shfl_xor(qp, 1, 64);
        qp += __shfl_xor(qp, 2, 64);
        qp += __shfl_xor(qp, 4, 64);
        if ((t & 7) == 0) qn[r] = 1.f / fmaxf(sqrtf(qp), EPSN);
    }
    __syncthreads();               // q LDS + qn ready; NO barriers after this

    // ---- zero-barrier K-loop ----
    f32x4 acc[4];
    #pragma unroll
    for (int m = 0; m < 4; ++m) acc[m] = (f32x4){0.f, 0.f, 0.f, 0.f};
    float epart = 0.f;

    #pragma unroll
    for (int ch = 0; ch < NCH; ++ch) {
        float4 n20 = z, n21 = z;
        if (ch + 2 < NCH) {            // 2-deep register prefetch
            n20 = ev ? erp[(ch + 2) * KC]     : z;
            n21 = ev ? erp[(ch + 2) * KC + 1] : z;
        }
        // convert this chunk's e slice to hi/lo bf16; e-norm partial (recon)
        bf16x8 bh, bl;
        {
            float xs[8] = {cur0.x, cur0.y, cur0.z, cur0.w,
                           cur1.x, cur1.y, cur1.z, cur1.w};
            #pragma unroll
            for (int i = 0; i < 8; ++i) {
                __bf16 h = (__bf16)xs[i];
                __bf16 l = (__bf16)(xs[i] - (float)h);
                bh[i] = h; bl[i] = l;
                float x = (float)h + (float)l;
                epart = fmaf(x, x, epart);
            }
        }
        #pragma unroll
        for (int m = 0; m < 4; ++m) {
            bf16x8 ah = *(const bf16x8*)&sm.st.qh[m * 16 + mrow][ch * 32 + kg * 8];
            bf16x8 al = *(const bf16x8*)&sm.st.ql[m * 16 + mrow][ch * 32 + kg * 8];
            acc[m] = __builtin_amdgcn_mfma_f32_16x16x32_bf16(ah, bh, acc[m], 0, 0, 0);
            acc[m] = __builtin_amdgcn_mfma_f32_16x16x32_bf16(ah, bl, acc[m], 0, 0, 0);
            acc[m] = __builtin_amdgcn_mfma_f32_16x16x32_bf16(al, bh, acc[m], 0, 0, 0);
        }
        cur0 = nxt0; cur1 = nxt1;
        nxt0 = n20;  nxt1 = n21;
    }

    // ---- e-norms (reduce kg groups) ----
    epart += __shfl_xor(epart, 16, 64);
    epart += __shfl_xor(epart, 32, 64);
    if (kg == 0) en[w * 16 + mrow] = 1.f / fmaxf(sqrtf(epart), EPSN);

    __syncthreads();               // all waves done with q LDS; en visible

    // ---- scores -> LDS: D[b = m*16+kg*4+r][c = w*16+mrow] ----
    const float ev2 = en[w * 16 + mrow];
    #pragma unroll
    for (int m = 0; m < 4; ++m) {
        #pragma unroll
        for (int r = 0; r < 4; ++r) {
            int b = m * 16 + kg * 4 + r;
            sm.ep.sc[b][w * 16 + mrow] = acc[m][r] * qn[b] * ev2;
        }
    }
    __syncthreads();

    // ---- per-(b,tile) top-8 + contiguous store (R14/R15 pattern, 8 groups) --
    const int sb = t & 63;         // b
    const int g  = t >> 6;         // c-group (16 c's each)
    u64 ls[8];
    #pragma unroll
    for (int j = 0; j < 8; ++j) ls[j] = 0ull;
    #pragma unroll
    for (int i2 = 0; i2 < 16; ++i2) {
        int cl = g * 16 + i2;
        int c  = c0 + cl;
        if (c < C && sb < B) insert8(ls, make_key(sm.ep.sc[sb][cl], c));
    }
    if (g != 0) {                  // sp disjoint from sc: no alias hazard
        #pragma unroll
        for (int r = 0; r < 8; ++r) sm.ep.sp[sb][g - 1][r] = ls[r];
    }
    __syncthreads();
    if (g == 0) {                  // wave 0: merge 8x8 -> 8, contiguous store
        #pragma unroll
        for (int gg = 0; gg < 7; ++gg)
            #pragma unroll
            for (int r = 0; r < 8; ++r) insert8(ls, sm.ep.sp[sb][gg][r]);
        u64* dst = cand + (((size_t)blockIdx.x * 64) + sb) * 8;
        #pragma unroll
        for (int r = 0; r < 8; ++r) dst[r] = ls[r];
    }
}

// ---------------------------------------------------------------------------
// Kernel 2 (merge): identical to round 14/15. B blocks; thread t reads tile
// t's 8 sorted keys (64B contiguous), early-break insert, block merge.
// ---------------------------------------------------------------------------
__global__ __launch_bounds__(256)
void merge_kernel(const u64* __restrict__ cand,
                  float* __restrict__ scores_out, int* __restrict__ top_idx,
                  int B, int NT) {
    __shared__ u64 sh[256 * 8];   // 16 KB
    const int b = blockIdx.x, t = threadIdx.x;

    u64 ls[8];
    #pragma unroll
    for (int j = 0; j < 8; ++j) ls[j] = 0ull;

    for (int tile = t; tile < NT; tile += 256) {
        const u64* pp = cand + (((size_t)tile * 64) + b) * 8;
        #pragma unroll
        for (int r = 0; r < 8; ++r) {
            u64 k = pp[r];
            if (k <= ls[7]) break;          // pp[] sorted descending
            ls[7] = k;
            #pragma unroll
            for (int q = 7; q > 0; --q)
                if (ls[q] > ls[q-1]) { u64 tmp = ls[q]; ls[q] = ls[q-1]; ls[q-1] = tmp; }
        }
    }

    #pragma unroll
    for (int j = 0; j < 8; ++j) sh[t * 8 + j] = ls[j];
    __syncthreads();

    if (t < 64) {
        u64 m[8];
        #pragma unroll
        for (int j = 0; j < 8; ++j) m[j] = 0ull;
        for (int tt = 0; tt < 4; ++tt) {
            const u64* pp = &sh[(t * 4 + tt) * 8];
            #pragma unroll
            for (int j = 0; j < 8; ++j) {
                u64 k = pp[j];
                if (k <= m[7]) break;           // pp[] sorted descending
                m[7] = k;
                #pragma unroll
                for (int q = 7; q > 0; --q)
                    if (m[q] > m[q-1]) { u64 tmp = m[q]; m[q] = m[q-1]; m[q-1] = tmp; }
            }
        }
        for (int r = 0; r < 8; ++r) {
            u64 best = m[0];
            #pragma unroll
            for (int off = 32; off; off >>= 1) {
                u64 o = __shfl_xor(best, off, 64);
                if (o > best) best = o;
            }
            if (m[0] == best) {                 // unique owner pops
                #pragma unroll
                for (int q = 0; q < 7; ++q) m[q] = m[q+1];
                m[7] = 0ull;
            }
            if (t == 0) {
                scores_out[b * 8 + r] = key_val(best);
                top_idx[b * 8 + r]    = key_idx(best);
            }
        }
    }
}

// ---------------------------------------------------------------------------
// Kernel 3 (gather): identical to round 14/15.
// ---------------------------------------------------------------------------
__global__ __launch_bounds__(256)
void gather_kernel(const float* __restrict__ episodes,    // [C][S][256]
                   const float* __restrict__ compressed,  // [C][Cs][256]
                   const void* __restrict__ is_comp,
                   const int* __restrict__ top_idx,       // [B*8]
                   const int* __restrict__ flags,
                   float* __restrict__ out,               // [B*8][S*256]
                   int S, int Cs) {
    const int bj  = blockIdx.x >> 1;
    const int h   = blockIdx.x & 1;
    const int idx = top_idx[bj];
    const int f_off = flags[0], f_gt1 = flags[1];

    bool comp;
    if      (f_gt1) comp = ((const float*)is_comp)[idx] != 0.f;
    else if (f_off) comp = ((const unsigned char*)is_comp)[idx] != 0;
    else            comp = ((const int*)is_comp)[idx] != 0;

    const int n4   = S * H4;       // 2048
    const int c4   = Cs * H4;      // 1024
    const int half = n4 >> 1;      // 1024
    const int v0   = h * half;

    const float4* full4 = (const float4*)episodes   + (size_t)idx * n4;
    const float4* cmp4  = (const float4*)compressed + (size_t)idx * c4;
    float4* out4 = (float4*)out + (size_t)bj * n4;
    const float4 z = make_float4(0.f, 0.f, 0.f, 0.f);

    if (comp) {
        #pragma unroll 4
        for (int v = v0 + threadIdx.x; v < v0 + half; v += 256)
            out4[v] = (v < c4) ? cmp4[v] : z;
    } else {
        #pragma unroll 4
        for (int v = v0 + threadIdx.x; v < v0 + half; v += 256)
            out4[v] = full4[v];
    }
}

// ---------------------------------------------------------------------------
extern "C" void kernel_launch(void* const* d_in, const int* in_sizes, int n_in,
                              void* d_out, int out_size, void* d_ws, size_t ws_size,
                              hipStream_t stream) {
    const float* query      = (const float*)d_in[0];
    const float* episodes   = (const float*)d_in[1];
    const float* compressed = (const float*)d_in[2];
    const float* emb        = (const float*)d_in[3];
    const void*  is_comp    = d_in[4];
    // d_in[5] is k (device scalar); fixed at 8 by the problem setup.

    const int B  = in_sizes[0] / HDIM;        // 64
    const int C  = in_sizes[3] / HDIM;        // 20000
    const int S  = in_sizes[1] / (C * HDIM);  // 32
    const int Cs = in_sizes[2] / (C * HDIM);  // 16
    const int K  = 8;
    const int NT = (C + CT - 1) / CT;         // 157

    float* out        = (float*)d_out;
    float* scores_out = out + (size_t)B * K * S * HDIM;

    // scratch layout in d_ws (fully rewritten every call -> deterministic):
    u64*  cand    = (u64*)d_ws;                          // NT*64*8 u64 = 0.64 MB
    int*  top_idx = (int*)(cand + (size_t)NT * 64 * 8);  // B*K ints
    int*  flags   = top_idx + B * K;                     // 2 ints

    sims_kernel<<<NT + 1, 512, 0, stream>>>(
        (const float4*)query, (const float4*)emb, (const u32*)is_comp,
        cand, flags, C, B, NT);
    merge_kernel<<<B, 256, 0, stream>>>(cand, scores_out, top_idx, B, NT);
    gather_kernel<<<B * K * 2, 256, 0, stream>>>(episodes, compressed, is_comp,
                                                 top_idx, flags, out, S, Cs);
}